// Round 12
// baseline (593.780 us; speedup 1.0000x reference)
//
#include <hip/hip_runtime.h>

#define T_ 32
#define B_ 32
#define S_ 64
#define C_ 1024
#define H_ 1024
#define NWG 64
#define HSLOT 32768  // ushorts per h ring slot / per x_t slab (32 x 1024)

typedef __attribute__((ext_vector_type(8))) short bf16x8;
typedef __attribute__((ext_vector_type(4))) float f32x4;

// d_out layout (float offsets): outputs[32*32*1024], h[32*1024], c[32*1024], attn[32*32*64]
#define OUT_H   1048576
#define OUT_CC  1081344
#define OUT_AT  1114112

__device__ __forceinline__ ushort f2b(float f) {
  unsigned u = __float_as_uint(f);
  unsigned r = (u + 0x7FFFu + ((u >> 16) & 1u)) >> 16;
  return (ushort)r;
}
__device__ __forceinline__ float b2f(ushort h) {
  return __uint_as_float(((unsigned)h) << 16);
}

// ---- init: cvt inp -> inpb; Wih/Whh -> Wcat[4096][2048] (k<1024 = Wih, k>=1024 = Whh);
//      v = W2@W1_x; bias; zero hring slot 0; zero flags ----
__global__ __launch_bounds__(256) void k_init(const float* __restrict__ inp, ushort* __restrict__ inpb,
                                              const float* __restrict__ Wih, const float* __restrict__ Whh,
                                              ushort* __restrict__ Wcat,
                                              const float* __restrict__ W1, const float* __restrict__ W2,
                                              const float* __restrict__ bih, const float* __restrict__ bhh,
                                              float* __restrict__ v, float* __restrict__ bias,
                                              ushort* __restrict__ hring, unsigned* __restrict__ flags) {
  int blk = blockIdx.x, tid = threadIdx.x;
  if (blk < 512) {
    // inp cvt: flat
    size_t i = ((size_t)blk * 256 + tid) * 8;
    float4 v0 = *reinterpret_cast<const float4*>(inp + i);
    float4 v1 = *reinterpret_cast<const float4*>(inp + i + 4);
    uint4 o;
    o.x = (unsigned)f2b(v0.x) | ((unsigned)f2b(v0.y) << 16);
    o.y = (unsigned)f2b(v0.z) | ((unsigned)f2b(v0.w) << 16);
    o.z = (unsigned)f2b(v1.x) | ((unsigned)f2b(v1.y) << 16);
    o.w = (unsigned)f2b(v1.z) | ((unsigned)f2b(v1.w) << 16);
    *reinterpret_cast<uint4*>(inpb + i) = o;
  } else if (blk < 4608) {
    // Wih (blocks 512..2559) or Whh (2560..4607) into Wcat halves
    const float* src = (blk < 2560) ? Wih : Whh;
    int base = (blk < 2560) ? (blk - 512) : (blk - 2560);
    int koff = (blk < 2560) ? 0 : 1024;
    size_t i = ((size_t)base * 256 + tid) * 8;
    int j = (int)(i >> 10), k = (int)(i & 1023);
    float4 v0 = *reinterpret_cast<const float4*>(src + i);
    float4 v1 = *reinterpret_cast<const float4*>(src + i + 4);
    uint4 o;
    o.x = (unsigned)f2b(v0.x) | ((unsigned)f2b(v0.y) << 16);
    o.y = (unsigned)f2b(v0.z) | ((unsigned)f2b(v0.w) << 16);
    o.z = (unsigned)f2b(v1.x) | ((unsigned)f2b(v1.y) << 16);
    o.w = (unsigned)f2b(v1.z) | ((unsigned)f2b(v1.w) << 16);
    *reinterpret_cast<uint4*>(Wcat + (size_t)j * 2048 + koff + k) = o;
  } else if (blk < 4612) {
    int c = (blk - 4608) * 256 + tid;
    float acc = 0.f;
#pragma unroll 8
    for (int a = 0; a < 128; ++a) acc += W1[a * 2048 + 1024 + c] * W2[a];
    v[c] = acc;
  } else if (blk < 4628) {
    int jj = (blk - 4612) * 256 + tid;
    bias[jj] = bih[jj] + bhh[jj];
  } else if (blk < 4632) {
    unsigned* hz = reinterpret_cast<unsigned*>(hring);
    int base = (blk - 4628) * 4096;
    for (int i = 0; i < 16; ++i) hz[base + i * 256 + tid] = 0u;
  } else {
    for (int i = 0; i < 4; ++i) flags[i * 256 + tid] = 0u;
  }
}

// ---- attention (time-invariant) + outputs/attn broadcast to all t (r8-proven) ----
__global__ __launch_bounds__(256) void k_attn(const float* __restrict__ ctx, const float* __restrict__ v,
                                              float* __restrict__ out) {
  int b = blockIdx.x, tid = threadIdx.x;
  int lane = tid & 63, w = tid >> 6;
  __shared__ float v_s[1024];
  __shared__ float sc_s[64];
  __shared__ float att_s[64];
  for (int i = 0; i < 4; ++i) v_s[tid + i * 256] = v[tid + i * 256];
  __syncthreads();
  for (int si = 0; si < 16; ++si) {
    int s = w * 16 + si;
    const float* xr = ctx + (size_t)(s * B_ + b) * C_;
    float acc = 0.f;
#pragma unroll
    for (int i = 0; i < 16; ++i) { int c = lane + i * 64; acc += xr[c] * v_s[c]; }
    for (int off = 32; off; off >>= 1) acc += __shfl_down(acc, off);
    if (lane == 0) sc_s[s] = acc;
  }
  __syncthreads();
  if (tid < 64) {
    float val = sc_s[tid];
    float mx = val;
    for (int off = 32; off; off >>= 1) mx = fmaxf(mx, __shfl_xor(mx, off));
    float e = expf(val - mx);
    float sm = e;
    for (int off = 32; off; off >>= 1) sm += __shfl_xor(sm, off);
    att_s[tid] = e / sm;
  }
  __syncthreads();
  const float4* ctx4 = reinterpret_cast<const float4*>(ctx);
  float4 a4 = {0.f, 0.f, 0.f, 0.f};
  for (int s = 0; s < 64; ++s) {
    float a = att_s[s];
    float4 x = ctx4[(size_t)(s * B_ + b) * 256 + tid];
    a4.x += a * x.x; a4.y += a * x.y; a4.z += a * x.z; a4.w += a * x.w;
  }
#pragma unroll 4
  for (int t = 0; t < T_; ++t)
    reinterpret_cast<float4*>(out + (size_t)(t * B_ + b) * C_)[tid] = a4;
  if (tid < 64) {
    float av = att_s[tid];
#pragma unroll 4
    for (int t = 0; t < T_; ++t) out[OUT_AT + (t * B_ + b) * 64 + tid] = av;
  }
}

// ---- persistent recurrence, fused K=2048 GEMM per step ----
// 64 WGs x 1024 threads. WG owns hidx [16*wg,16*wg+16) x 4 gates. Wave w: q=w&3, ks=w>>2
// (512-wide K-slice of the concatenated [x;h] operand; ks<2 = x-part, ks>=2 = h-part).
// Wcat fragments register-resident (16 x bf16x8 = 64 VGPR). Per step: ONE staging phase
// (x-half from inpb, h-half from hring slot t), ONE MFMA phase (32 MFMAs/wave), K-reduce
// via LDS atomicAdd into 8KB double-buffered red, epilogue (bias in regs, no xpT!),
// publish h via agent-scope stores + monotonic flag; w0 polls 64 flags. No cache fences.
__global__ __launch_bounds__(1024, 4) void k_rec(const ushort* __restrict__ Wcat, const ushort* __restrict__ inpb,
                                                 ushort* __restrict__ hring, const float* __restrict__ bias,
                                                 float* __restrict__ out, unsigned* __restrict__ flags) {
  int tid = threadIdx.x, lane = tid & 63, w = tid >> 6;
  int wg = blockIdx.x;
  int q = w & 3, ks = w >> 2;
  int g = lane >> 4, r = lane & 15;
  int j = (r >> 2) * 1024 + wg * 16 + q * 4 + (r & 3);
  bf16x8 a[16];
  {
    const ushort* ap = Wcat + (size_t)j * 2048 + ks * 512 + g * 8;
#pragma unroll
    for (int kk = 0; kk < 16; ++kk) a[kk] = *reinterpret_cast<const bf16x8*>(ap + kk * 32);
  }
  __shared__ uint4 buf[8192];          // 128 KB: [row(32)][c16(256)], idx = row*256 + (c16 ^ (row&7))
  __shared__ float red[2][4][16][32];  // 16 KB double-buffered K-partials (atomicAdd)
  __shared__ __align__(16) ushort hs[32][16];
  float c_reg = 0.f;
  int eb = tid & 31, hl = (tid >> 5) & 3, qq = tid >> 7;  // epilogue cell (tid<512)
  int ehidx = wg * 16 + qq * 4 + hl;
  float bs_i = 0.f, bs_f = 0.f, bs_g = 0.f, bs_o = 0.f;
  if (tid < 512) {
    bs_i = bias[ehidx];
    bs_f = bias[1024 + ehidx];
    bs_g = bias[2048 + ehidx];
    bs_o = bias[3072 + ehidx];
  }
  int c16s = tid & 255, rowb = tid >> 8;
  int swz_w[8];
#pragma unroll
  for (int i = 0; i < 8; ++i) {
    int row = rowb + i * 4;
    swz_w[i] = row * 256 + (c16s ^ (row & 7));
  }

#pragma unroll 1
  for (int t = 0; t < T_; ++t) {
    int p = t & 1;
    // ---- poll (w0 only): h_t published by all 64 producers ----
    if (t > 0 && w == 0) {
      for (;;) {
        unsigned vfl = __hip_atomic_load(&flags[lane * 16], __ATOMIC_RELAXED, __HIP_MEMORY_SCOPE_AGENT);
        if (__all((int)(vfl >= (unsigned)t))) break;
        __builtin_amdgcn_s_sleep(1);
      }
    }
    __syncthreads();  // S1
    // ---- zero next red buffer (and red[0] at t=0) ----
    {
      float* z = &red[p ^ 1][0][0][0];
      z[tid] = 0.f; z[tid + 1024] = 0.f;
      if (t == 0) {
        float* z0 = &red[0][0][0][0];
        z0[tid] = 0.f; z0[tid + 1024] = 0.f;
      }
    }
    // ---- stage [x_t ; h_t] -> buf (x-half c16<128, h-half c16>=128; wave-uniform split) ----
    {
      const ushort* xsrc = inpb + (size_t)t * HSLOT;
      const ushort* hsrc = hring + (size_t)t * HSLOT;
      const ushort* colb = (c16s < 128) ? (xsrc + c16s * 8) : (hsrc + (c16s - 128) * 8);
#pragma unroll
      for (int i = 0; i < 8; ++i) {
        int row = rowb + i * 4;
        buf[swz_w[i]] = *reinterpret_cast<const uint4*>(colb + (size_t)row * 1024);
      }
    }
    __syncthreads();  // S2
    // ---- MFMA: K=512 slice, 16 frag-steps x 2 (b 0-15, 16-31) ----
    f32x4 acc0 = (f32x4)(0.f), acc1 = (f32x4)(0.f);
    int cb = ks * 64 + g;
#pragma unroll
    for (int kk = 0; kk < 16; ++kk) {
      int c16 = cb + kk * 4;
      int x0 = r * 256 + (c16 ^ (r & 7));
      bf16x8 b0 = *reinterpret_cast<const bf16x8*>(&buf[x0]);
      bf16x8 b1 = *reinterpret_cast<const bf16x8*>(&buf[x0 + 16 * 256]);
      acc0 = __builtin_amdgcn_mfma_f32_16x16x32_bf16(a[kk], b0, acc0, 0, 0, 0);
      acc1 = __builtin_amdgcn_mfma_f32_16x16x32_bf16(a[kk], b1, acc1, 0, 0, 0);
    }
#pragma unroll
    for (int e = 0; e < 4; ++e) {
      atomicAdd(&red[p][q][g * 4 + e][r], acc0[e]);
      atomicAdd(&red[p][q][g * 4 + e][r + 16], acc1[e]);
    }
    __syncthreads();  // S3
    if (tid < 512) {
      float ig = red[p][qq][0 + hl][eb]  + bs_i;
      float fg = red[p][qq][4 + hl][eb]  + bs_f;
      float gg = red[p][qq][8 + hl][eb]  + bs_g;
      float og = red[p][qq][12 + hl][eb] + bs_o;
      float si = 1.f / (1.f + __expf(-ig));
      float sf = 1.f / (1.f + __expf(-fg));
      float so = 1.f / (1.f + __expf(-og));
      float c_new = sf * c_reg + si * tanhf(gg);
      float h_new = so * tanhf(c_new);
      c_reg = c_new;
      hs[eb][qq * 4 + hl] = f2b(h_new);
      if (t == T_ - 1) {
        out[OUT_H + eb * 1024 + ehidx] = h_new;
        out[OUT_CC + eb * 1024 + ehidx] = c_new;
      }
    }
    __syncthreads();  // S4: hs ready
    if (t != T_ - 1 && w == 0) {
      ushort* hout = hring + (size_t)(t + 1) * HSLOT;
      int b = lane >> 1, half = lane & 1;
      uint4 vv = *reinterpret_cast<const uint4*>(&hs[b][half * 8]);
      unsigned* hp = reinterpret_cast<unsigned*>(hout) + b * 512 + wg * 8 + half * 4;
      __hip_atomic_store(hp + 0, vv.x, __ATOMIC_RELAXED, __HIP_MEMORY_SCOPE_AGENT);
      __hip_atomic_store(hp + 1, vv.y, __ATOMIC_RELAXED, __HIP_MEMORY_SCOPE_AGENT);
      __hip_atomic_store(hp + 2, vv.z, __ATOMIC_RELAXED, __HIP_MEMORY_SCOPE_AGENT);
      __hip_atomic_store(hp + 3, vv.w, __ATOMIC_RELAXED, __HIP_MEMORY_SCOPE_AGENT);
      asm volatile("s_waitcnt vmcnt(0)" ::: "memory");
      if (lane == 0)
        __hip_atomic_store(&flags[wg * 16], (unsigned)(t + 1), __ATOMIC_RELAXED, __HIP_MEMORY_SCOPE_AGENT);
    }
  }
}

extern "C" void kernel_launch(void* const* d_in, const int* in_sizes, int n_in,
                              void* d_out, int out_size, void* d_ws, size_t ws_size,
                              hipStream_t stream) {
  const float* inp = (const float*)d_in[0];
  const float* ctx = (const float*)d_in[1];
  const float* Wih = (const float*)d_in[2];
  const float* Whh = (const float*)d_in[3];
  const float* bih = (const float*)d_in[4];
  const float* bhh = (const float*)d_in[5];
  const float* W1  = (const float*)d_in[6];
  const float* W2  = (const float*)d_in[8];
  float* out = (float*)d_out;
  char* wsb = (char*)d_ws;

  float* v     = (float*)(wsb + 0);          // 4 KB
  float* bias  = (float*)(wsb + 4096);       // 16 KB
  ushort* hring = (ushort*)(wsb + 32768);    // 33 slots x 64 KB = 2112 KB
  ushort* inpb = (ushort*)(wsb + 2195456);   // 2 MB
  ushort* Wcat = (ushort*)(wsb + 4292608);   // 16 MB
  unsigned* flags = (unsigned*)(wsb + 21069824); // 4 KB (64 flags, 64B apart)

  hipLaunchKernelGGL(k_init, dim3(4633), dim3(256), 0, stream,
                     inp, inpb, Wih, Whh, Wcat, W1, W2, bih, bhh, v, bias, hring, flags);
  hipLaunchKernelGGL(k_attn, dim3(32), dim3(256), 0, stream, ctx, v, out);

  const ushort* Wcat_c = Wcat;
  const ushort* inpb_c = inpb;
  const float* bias_c = bias;
  void* kargs[6];
  kargs[0] = (void*)&Wcat_c;
  kargs[1] = (void*)&inpb_c;
  kargs[2] = (void*)&hring;
  kargs[3] = (void*)&bias_c;
  kargs[4] = (void*)&out;
  kargs[5] = (void*)&flags;
  hipLaunchCooperativeKernel((const void*)k_rec, dim3(NWG), dim3(1024), kargs, 0, stream);
}

// Round 15
// 196.827 us; speedup vs baseline: 3.0168x; 3.0168x over previous
//
#include <hip/hip_runtime.h>

#define T_ 32
#define B_ 32
#define S_ 64
#define C_ 1024
#define H_ 1024
#define NWG 64
#define HSLOT 32768  // ushorts per h ring slot / per x_t slab (32 x 1024)

typedef __attribute__((ext_vector_type(8))) short bf16x8;
typedef __attribute__((ext_vector_type(4))) float f32x4;

// d_out layout (float offsets): outputs[32*32*1024], h[32*1024], c[32*1024], attn[32*32*64]
#define OUT_H   1048576
#define OUT_CC  1081344
#define OUT_AT  1114112

__device__ __forceinline__ ushort f2b(float f) {
  unsigned u = __float_as_uint(f);
  unsigned r = (u + 0x7FFFu + ((u >> 16) & 1u)) >> 16;
  return (ushort)r;
}
__device__ __forceinline__ float b2f(ushort h) {
  return __uint_as_float(((unsigned)h) << 16);
}

// ---------------- init: cvt inp/Wih/Whh to bf16, v = W2@W1_x, bias, zero h slot0, zero flags ----------------
__global__ __launch_bounds__(256) void k_init(const float* __restrict__ inp, ushort* __restrict__ inpb,
                                              const float* __restrict__ Wih, ushort* __restrict__ Wihb,
                                              const float* __restrict__ Whh, ushort* __restrict__ Whhb,
                                              const float* __restrict__ W1, const float* __restrict__ W2,
                                              const float* __restrict__ bih, const float* __restrict__ bhh,
                                              float* __restrict__ v, float* __restrict__ bias,
                                              ushort* __restrict__ hring, unsigned* __restrict__ flags) {
  int blk = blockIdx.x, tid = threadIdx.x;
  if (blk < 4608) {
    const float* src; ushort* dst; int base;
    if (blk < 512) { src = inp; dst = inpb; base = blk; }
    else if (blk < 2560) { src = Wih; dst = Wihb; base = blk - 512; }
    else { src = Whh; dst = Whhb; base = blk - 2560; }
    size_t i = ((size_t)base * 256 + tid) * 8;
    float4 v0 = *reinterpret_cast<const float4*>(src + i);
    float4 v1 = *reinterpret_cast<const float4*>(src + i + 4);
    uint4 o;
    o.x = (unsigned)f2b(v0.x) | ((unsigned)f2b(v0.y) << 16);
    o.y = (unsigned)f2b(v0.z) | ((unsigned)f2b(v0.w) << 16);
    o.z = (unsigned)f2b(v1.x) | ((unsigned)f2b(v1.y) << 16);
    o.w = (unsigned)f2b(v1.z) | ((unsigned)f2b(v1.w) << 16);
    *reinterpret_cast<uint4*>(dst + i) = o;
  } else if (blk < 4612) {
    int c = (blk - 4608) * 256 + tid;
    float acc = 0.f;
#pragma unroll 8
    for (int a = 0; a < 128; ++a) acc += W1[a * 2048 + 1024 + c] * W2[a];
    v[c] = acc;
  } else if (blk < 4628) {
    int jj = (blk - 4612) * 256 + tid;
    bias[jj] = bih[jj] + bhh[jj];
  } else if (blk < 4632) {
    unsigned* hz = reinterpret_cast<unsigned*>(hring);
    int base = (blk - 4628) * 4096;
    for (int i = 0; i < 16; ++i) hz[base + i * 256 + tid] = 0u;
  } else {
    for (int i = 0; i < 4; ++i) flags[i * 256 + tid] = 0u;
  }
}

// ---------------- cooperative kernel: 96 WGs x 1024 threads ----------------
// WGs 0..63: persistent recurrence + fused x-projection (r11 structure, measured 5.25 us/step).
// WGs 64..95: attention (time-invariant) + outputs/attn broadcast on otherwise-idle CUs; exit.
__global__ __launch_bounds__(1024, 4) void k_rec(const ushort* __restrict__ Whhb, const ushort* __restrict__ Wihb,
                                                 const ushort* __restrict__ inpb, ushort* __restrict__ hring,
                                                 const float* __restrict__ ctx, const float* __restrict__ v,
                                                 const float* __restrict__ bias,
                                                 float* __restrict__ out, unsigned* __restrict__ flags) {
  int tid = threadIdx.x, lane = tid & 63, w = tid >> 6;
  int wg = blockIdx.x;

  __shared__ uint4 hl4[4096];           // 64 KB staging (x_t, then h): idx = row*128 + (c16 ^ (row&7))
  __shared__ float red[4][4][16][32];   // 32 KB K-slice partials
  __shared__ __align__(16) ushort hs[32][16];
  __shared__ float v_s[1024];           // attention path
  __shared__ float sc_s[64];
  __shared__ float att_s[64];

  if (wg >= NWG) {
    // ================= attention path (1 batch per WG; barriers hit by all 1024 threads) =================
    int b = wg - NWG;
    v_s[tid] = v[tid];
    __syncthreads();
    {
      int s = w * 4;
#pragma unroll
      for (int si = 0; si < 4; ++si, ++s) {
        const float* xr = ctx + (size_t)(s * B_ + b) * C_;
        float acc = 0.f;
#pragma unroll
        for (int i = 0; i < 16; ++i) { int c = lane + i * 64; acc += xr[c] * v_s[c]; }
        for (int off = 32; off; off >>= 1) acc += __shfl_down(acc, off);
        if (lane == 0) sc_s[s] = acc;
      }
    }
    __syncthreads();
    if (tid < 64) {
      float val = sc_s[tid];
      float mx = val;
      for (int off = 32; off; off >>= 1) mx = fmaxf(mx, __shfl_xor(mx, off));
      float e = expf(val - mx);
      float sm = e;
      for (int off = 32; off; off >>= 1) sm += __shfl_xor(sm, off);
      att_s[tid] = e / sm;
    }
    __syncthreads();
    if (tid < 256) {
      const float4* ctx4 = reinterpret_cast<const float4*>(ctx);
      float4 a4 = {0.f, 0.f, 0.f, 0.f};
      for (int s = 0; s < 64; ++s) {
        float a = att_s[s];
        float4 x = ctx4[(size_t)(s * B_ + b) * 256 + tid];
        a4.x += a * x.x; a4.y += a * x.y; a4.z += a * x.z; a4.w += a * x.w;
      }
#pragma unroll 4
      for (int t = 0; t < T_; ++t)
        reinterpret_cast<float4*>(out + (size_t)(t * B_ + b) * C_)[tid] = a4;
    }
    if (tid < 64) {
      float av = att_s[tid];
#pragma unroll 4
      for (int t = 0; t < T_; ++t) out[OUT_AT + (t * B_ + b) * 64 + tid] = av;
    }
    return;
  }

  // ================= recurrence path (r11 structure) =================
  int q = w & 3, ks = w >> 2;
  int g = lane >> 4, r = lane & 15;
  int hidx0 = wg * 16 + q * 4;
  int kbase = ks * 256;
  int j = (r >> 2) * 1024 + hidx0 + (r & 3);
  bf16x8 ah[8], ax[8];
  {
    const ushort* ap = Whhb + (size_t)j * 1024 + kbase + g * 8;
    const ushort* axp = Wihb + (size_t)j * 1024 + kbase + g * 8;
#pragma unroll
    for (int kk = 0; kk < 8; ++kk) {
      ah[kk] = *reinterpret_cast<const bf16x8*>(ap + kk * 32);
      ax[kk] = *reinterpret_cast<const bf16x8*>(axp + kk * 32);
    }
  }
  float c_reg = 0.f;
  int eb = tid & 31, hl = (tid >> 5) & 3, qq = tid >> 7;  // epilogue cell (tid<512)
  int ehidx = wg * 16 + qq * 4 + hl;
  float bs_i = 0.f, bs_f = 0.f, bs_g = 0.f, bs_o = 0.f;
  if (tid < 512) {
    bs_i = bias[ehidx];
    bs_f = bias[1024 + ehidx];
    bs_g = bias[2048 + ehidx];
    bs_o = bias[3072 + ehidx];
  }
  int cb = ks * 32 + g;

#pragma unroll 1
  for (int t = 0; t < T_; ++t) {
    // ---- phase X: stage x_t (no dependency) and accumulate W_ih @ x_t ----
    {
      const uint4* s4 = reinterpret_cast<const uint4*>(inpb + (size_t)t * HSLOT);
      uint4 v0 = s4[tid], v1 = s4[tid + 1024], v2 = s4[tid + 2048], v3 = s4[tid + 3072];
      int c0 = tid, c1 = tid + 1024, c2 = tid + 2048, c3 = tid + 3072;
      hl4[(c0 >> 7) * 128 + ((c0 & 127) ^ ((c0 >> 7) & 7))] = v0;
      hl4[(c1 >> 7) * 128 + ((c1 & 127) ^ ((c1 >> 7) & 7))] = v1;
      hl4[(c2 >> 7) * 128 + ((c2 & 127) ^ ((c2 >> 7) & 7))] = v2;
      hl4[(c3 >> 7) * 128 + ((c3 & 127) ^ ((c3 >> 7) & 7))] = v3;
    }
    __syncthreads();
    f32x4 acc0 = (f32x4)(0.f), acc1 = (f32x4)(0.f);
#pragma unroll
    for (int kk = 0; kk < 8; ++kk) {
      int c16 = cb + kk * 4;
      bf16x8 b0 = *reinterpret_cast<const bf16x8*>(&hl4[r * 128 + (c16 ^ (r & 7))]);
      bf16x8 b1 = *reinterpret_cast<const bf16x8*>(&hl4[(r + 16) * 128 + (c16 ^ (r & 7))]);
      acc0 = __builtin_amdgcn_mfma_f32_16x16x32_bf16(ax[kk], b0, acc0, 0, 0, 0);
      acc1 = __builtin_amdgcn_mfma_f32_16x16x32_bf16(ax[kk], b1, acc1, 0, 0, 0);
    }
    // ---- poll: single wave, all 64 producer flags, one 64-lane bypass load ----
    if (t > 0 && w == 0) {
      for (;;) {
        unsigned vfl = __hip_atomic_load(&flags[lane * 16], __ATOMIC_RELAXED, __HIP_MEMORY_SCOPE_AGENT);
        if (__all((int)(vfl >= (unsigned)t))) break;
        __builtin_amdgcn_s_sleep(1);
      }
    }
    __syncthreads();  // gates h restage; all waves done reading x from hl4
    // ---- phase H: stage h slot t, accumulate W_hh @ h ----
    {
      const uint4* s4 = reinterpret_cast<const uint4*>(hring + (size_t)t * HSLOT);
      uint4 v0 = s4[tid], v1 = s4[tid + 1024], v2 = s4[tid + 2048], v3 = s4[tid + 3072];
      int c0 = tid, c1 = tid + 1024, c2 = tid + 2048, c3 = tid + 3072;
      hl4[(c0 >> 7) * 128 + ((c0 & 127) ^ ((c0 >> 7) & 7))] = v0;
      hl4[(c1 >> 7) * 128 + ((c1 & 127) ^ ((c1 >> 7) & 7))] = v1;
      hl4[(c2 >> 7) * 128 + ((c2 & 127) ^ ((c2 >> 7) & 7))] = v2;
      hl4[(c3 >> 7) * 128 + ((c3 & 127) ^ ((c3 >> 7) & 7))] = v3;
    }
    __syncthreads();
#pragma unroll
    for (int kk = 0; kk < 8; ++kk) {
      int c16 = cb + kk * 4;
      bf16x8 b0 = *reinterpret_cast<const bf16x8*>(&hl4[r * 128 + (c16 ^ (r & 7))]);
      bf16x8 b1 = *reinterpret_cast<const bf16x8*>(&hl4[(r + 16) * 128 + (c16 ^ (r & 7))]);
      acc0 = __builtin_amdgcn_mfma_f32_16x16x32_bf16(ah[kk], b0, acc0, 0, 0, 0);
      acc1 = __builtin_amdgcn_mfma_f32_16x16x32_bf16(ah[kk], b1, acc1, 0, 0, 0);
    }
#pragma unroll
    for (int e = 0; e < 4; ++e) {
      red[q][ks][g * 4 + e][r] = acc0[e];
      red[q][ks][g * 4 + e][r + 16] = acc1[e];
    }
    __syncthreads();
    if (tid < 512) {
      float ig = red[qq][0][0 + hl][eb]  + red[qq][1][0 + hl][eb]  + red[qq][2][0 + hl][eb]  + red[qq][3][0 + hl][eb]  + bs_i;
      float fg = red[qq][0][4 + hl][eb]  + red[qq][1][4 + hl][eb]  + red[qq][2][4 + hl][eb]  + red[qq][3][4 + hl][eb]  + bs_f;
      float gg = red[qq][0][8 + hl][eb]  + red[qq][1][8 + hl][eb]  + red[qq][2][8 + hl][eb]  + red[qq][3][8 + hl][eb]  + bs_g;
      float og = red[qq][0][12 + hl][eb] + red[qq][1][12 + hl][eb] + red[qq][2][12 + hl][eb] + red[qq][3][12 + hl][eb] + bs_o;
      float si = 1.f / (1.f + __expf(-ig));
      float sf = 1.f / (1.f + __expf(-fg));
      float so = 1.f / (1.f + __expf(-og));
      float c_new = sf * c_reg + si * tanhf(gg);
      float h_new = so * tanhf(c_new);
      c_reg = c_new;
      hs[eb][qq * 4 + hl] = f2b(h_new);
      if (t == T_ - 1) {
        out[OUT_H + eb * 1024 + ehidx] = h_new;
        out[OUT_CC + eb * 1024 + ehidx] = c_new;
      }
    }
    __syncthreads();  // hs ready
    if (t != T_ - 1 && w == 0) {
      // publish h slice via agent-scope (coherence-point) dword stores + monotonic flag
      ushort* hout = hring + (size_t)(t + 1) * HSLOT;
      int b = lane >> 1, half = lane & 1;
      uint4 vv = *reinterpret_cast<const uint4*>(&hs[b][half * 8]);
      unsigned* hp = reinterpret_cast<unsigned*>(hout) + b * 512 + wg * 8 + half * 4;
      __hip_atomic_store(hp + 0, vv.x, __ATOMIC_RELAXED, __HIP_MEMORY_SCOPE_AGENT);
      __hip_atomic_store(hp + 1, vv.y, __ATOMIC_RELAXED, __HIP_MEMORY_SCOPE_AGENT);
      __hip_atomic_store(hp + 2, vv.z, __ATOMIC_RELAXED, __HIP_MEMORY_SCOPE_AGENT);
      __hip_atomic_store(hp + 3, vv.w, __ATOMIC_RELAXED, __HIP_MEMORY_SCOPE_AGENT);
      asm volatile("s_waitcnt vmcnt(0)" ::: "memory");
      if (lane == 0)
        __hip_atomic_store(&flags[wg * 16], (unsigned)(t + 1), __ATOMIC_RELAXED, __HIP_MEMORY_SCOPE_AGENT);
    }
  }
}

extern "C" void kernel_launch(void* const* d_in, const int* in_sizes, int n_in,
                              void* d_out, int out_size, void* d_ws, size_t ws_size,
                              hipStream_t stream) {
  const float* inp = (const float*)d_in[0];
  const float* ctx = (const float*)d_in[1];
  const float* Wih = (const float*)d_in[2];
  const float* Whh = (const float*)d_in[3];
  const float* bih = (const float*)d_in[4];
  const float* bhh = (const float*)d_in[5];
  const float* W1  = (const float*)d_in[6];
  const float* W2  = (const float*)d_in[8];
  float* out = (float*)d_out;
  char* wsb = (char*)d_ws;

  float* v     = (float*)(wsb + 0);          // 4 KB
  float* bias  = (float*)(wsb + 4096);       // 16 KB
  ushort* hring = (ushort*)(wsb + 32768);    // 33 slots x 64 KB = 2112 KB
  ushort* inpb = (ushort*)(wsb + 2195456);   // 2 MB
  ushort* Wihb = (ushort*)(wsb + 4292608);   // 8 MB
  ushort* Whhb = (ushort*)(wsb + 12681216);  // 8 MB
  unsigned* flags = (unsigned*)(wsb + 21069824); // 4 KB (64 flags, 64B apart)

  hipLaunchKernelGGL(k_init, dim3(4633), dim3(256), 0, stream,
                     inp, inpb, Wih, Wihb, Whh, Whhb, W1, W2, bih, bhh, v, bias, hring, flags);

  const ushort* Whhb_c = Whhb;
  const ushort* Wihb_c = Wihb;
  const ushort* inpb_c = inpb;
  const float* ctx_c = ctx;
  const float* v_c = v;
  const float* bias_c = bias;
  void* kargs[9];
  kargs[0] = (void*)&Whhb_c;
  kargs[1] = (void*)&Wihb_c;
  kargs[2] = (void*)&inpb_c;
  kargs[3] = (void*)&hring;
  kargs[4] = (void*)&ctx_c;
  kargs[5] = (void*)&v_c;
  kargs[6] = (void*)&bias_c;
  kargs[7] = (void*)&out;
  kargs[8] = (void*)&flags;
  hipLaunchCooperativeKernel((const void*)k_rec, dim3(NWG + 32), dim3(1024), kargs, 0, stream);
}